// Round 8
// baseline (399.726 us; speedup 1.0000x reference)
//
#include <hip/hip_runtime.h>
#include <hip/hip_bf16.h>
#include <stdint.h>

#define DM 1024
#define NPAT 8
#define LDS_A 0
#define LDS_B 65536

typedef __bf16 bf16x8_t __attribute__((ext_vector_type(8)));
typedef float f32x4_t __attribute__((ext_vector_type(4)));
typedef unsigned short u16;

typedef const __attribute__((address_space(1))) void* gas_ptr;
typedef __attribute__((address_space(3))) void* las_ptr;

__device__ __forceinline__ u16 f2bf(float x) {
  uint32_t u = __float_as_uint(x);
  uint32_t r = (u + 0x7FFFu + ((u >> 16) & 1u)) >> 16;  // RNE
  return (u16)r;
}

// ---------------- K0: proj_w f32 -> bf16 ----------------
__global__ __launch_bounds__(256) void k0_cvt_w(const float* __restrict__ w,
                                                u16* __restrict__ wb) {
  int i = blockIdx.x * 256 + threadIdx.x;
  float4 v = ((const float4*)w)[i];
  ushort4 o;
  o.x = f2bf(v.x); o.y = f2bf(v.y); o.z = f2bf(v.z); o.w = f2bf(v.w);
  ((ushort4*)wb)[i] = o;
}

// ---------------- K1: hopfield read + residual + cast (R7-verified) --------
__global__ __launch_bounds__(256) void k1_hopfield(const float* __restrict__ h,
                                                   const float* __restrict__ pat,
                                                   u16* __restrict__ A, int M) {
  __shared__ float patL[NPAT * DM];
  const int tid = threadIdx.x;
  {
    const float4* p4 = (const float4*)pat;
    float4* l4 = (float4*)patL;
#pragma unroll
    for (int i = 0; i < (NPAT * DM / 4) / 256; ++i)
      l4[i * 256 + tid] = p4[i * 256 + tid];
  }
  __syncthreads();

  const int lane = tid & 63;
  const int wid = (blockIdx.x << 2) | (tid >> 6);
  const int nw = gridDim.x << 2;
  const f32x4_t* h4 = (const f32x4_t*)h;
  const f32x4_t* pl4 = (const f32x4_t*)patL;
  ushort4* A4 = (ushort4*)A;

  for (int rp = wid; rp < (M >> 1); rp += nw) {
    const size_t r0 = (size_t)rp << 1;
    f32x4_t hv0[4], hv1[4];
#pragma unroll
    for (int j = 0; j < 4; ++j) {
      hv0[j] = __builtin_nontemporal_load(&h4[r0 * 256 + j * 64 + lane]);
      hv1[j] = __builtin_nontemporal_load(&h4[(r0 + 1) * 256 + j * 64 + lane]);
    }
    float d0[NPAT], d1[NPAT];
#pragma unroll
    for (int p = 0; p < NPAT; ++p) {
      float a = 0.f, b = 0.f;
#pragma unroll
      for (int j = 0; j < 4; ++j) {
        f32x4_t pv = pl4[p * 256 + j * 64 + lane];
#pragma unroll
        for (int e = 0; e < 4; ++e) {
          a = fmaf(hv0[j][e], pv[e], a);
          b = fmaf(hv1[j][e], pv[e], b);
        }
      }
      d0[p] = a; d1[p] = b;
    }
#pragma unroll
    for (int p = 0; p < NPAT; ++p) {
#pragma unroll
      for (int o = 32; o > 0; o >>= 1) {
        d0[p] += __shfl_xor(d0[p], o);
        d1[p] += __shfl_xor(d1[p], o);
      }
    }
    float m0 = d0[0], m1 = d1[0];
#pragma unroll
    for (int p = 1; p < NPAT; ++p) { m0 = fmaxf(m0, d0[p]); m1 = fmaxf(m1, d1[p]); }
    float s0 = 0.f, s1 = 0.f;
#pragma unroll
    for (int p = 0; p < NPAT; ++p) {
      d0[p] = __expf(d0[p] - m0); s0 += d0[p];
      d1[p] = __expf(d1[p] - m1); s1 += d1[p];
    }
    const float i0 = 1.f / s0, i1 = 1.f / s1;
#pragma unroll
    for (int p = 0; p < NPAT; ++p) { d0[p] *= i0; d1[p] *= i1; }

#pragma unroll
    for (int j = 0; j < 4; ++j) {
      f32x4_t a0 = hv0[j], a1 = hv1[j];
#pragma unroll
      for (int p = 0; p < NPAT; ++p) {
        f32x4_t pv = pl4[p * 256 + j * 64 + lane];
#pragma unroll
        for (int e = 0; e < 4; ++e) {
          a0[e] = fmaf(d0[p], pv[e], a0[e]);
          a1[e] = fmaf(d1[p], pv[e], a1[e]);
        }
      }
      ushort4 o0, o1;
      o0.x = f2bf(a0[0]); o0.y = f2bf(a0[1]); o0.z = f2bf(a0[2]); o0.w = f2bf(a0[3]);
      o1.x = f2bf(a1[0]); o1.y = f2bf(a1[1]); o1.z = f2bf(a1[2]); o1.w = f2bf(a1[3]);
      A4[r0 * 256 + j * 64 + lane] = o0;
      A4[(r0 + 1) * 256 + j * 64 + lane] = o1;
    }
  }
}

// ---------------- K2: persistent 256x(4x256) 8-phase GEMM, SPREAD stores ----
// R4's verified persistent schedule (uniform 8 loads/tile; vmcnt(4) u<=61,
// vmcnt(0) u==62, none u==63) + deferred epilogue:
//  - at u=16/32/48: acc2 = acc + bias (group g=u/16-1 final), acc=0, bvv
//    reloaded for the next group (used 16 tiles later — latency-safe).
//  - 8 C-stores per tile at TILE TOP for u>=16, from acc2 via a 16-case
//    switch on u&15 (wave-uniform; all acc2 indices compile-time).
//    Stores are issued ~5500cyc before the same tile's end vmcnt(4), which
//    retires them without stalling (they precede the waited loads in queue).
//  - group 3 written directly after the loop.
#define STAGE(basePtr, regionOff, kt, hf, bufOff)                                        \
  do {                                                                                   \
    const u16* _s = (basePtr) + (size_t)((hf)*128) * DM + (kt)*64;                       \
    char* _d = lds + (regionOff) + (bufOff) + (hf)*16384;                                \
    __builtin_amdgcn_global_load_lds((gas_ptr)(_s + go0), (las_ptr)(_d + L0), 16, 0, 0); \
    __builtin_amdgcn_global_load_lds((gas_ptr)(_s + go1), (las_ptr)(_d + L1), 16, 0, 0); \
  } while (0)

#define RD(p) (*(const bf16x8_t*)(p))

// case k: stores s = k*8+j, j=0..7:  m=k>>1, r=(k&1)*2+(j>>2), n=j&3
#define STCASE(k)                                                                  \
  case (k): {                                                                      \
    _Pragma("unroll") for (int j = 0; j < 8; ++j) {                                \
      const int mm = (k) >> 1, rr = ((k) & 1) * 2 + (j >> 2), nn = j & 3;          \
      C[(size_t)(rowB + mm * 16 + rr) * DM + colB2 + nn * 16] = acc2[mm][nn][rr];  \
    }                                                                              \
  } break;

__global__ __launch_bounds__(512, 2) void k2_gemm(const u16* __restrict__ A,
                                                  const u16* __restrict__ B,
                                                  const float* __restrict__ bias,
                                                  float* __restrict__ C, int M) {
  __shared__ __align__(16) char lds[131072];
  const int tid = threadIdx.x;
  const int lane = tid & 63;
  const int wave = tid >> 6;   // 0..7
  const int wm = wave >> 2;    // 0..1 -> A row-half
  const int wn = wave & 3;     // 0..3 -> B rows wn*64..+63
  const int r16 = lane & 15, kg = lane >> 4;

  const int tm = blockIdx.x;  // 256 blocks, 1/CU; A panel block-private
  const u16* Ab = A + (size_t)tm * 256 * DM;

  const uint32_t L0 = (uint32_t)tid * 16;
  const uint32_t L1 = 8192u + (uint32_t)tid * 16;
  const uint32_t S0 = L0 ^ (((L0 >> 7) & 7u) << 4);
  const uint32_t S1 = L1 ^ (((L1 >> 7) & 7u) << 4);
  const uint32_t go0 = (S0 >> 7) * DM + ((S0 & 127u) >> 1);
  const uint32_t go1 = (S1 >> 7) * DM + ((S1 & 127u) >> 1);

  const uint32_t flip = (uint32_t)(r16 & 7) << 4;
  const uint32_t aoff0 = ((uint32_t)(r16 * 128 + kg * 16)) ^ flip;
  const uint32_t aoff1 = ((uint32_t)(r16 * 128 + 64 + kg * 16)) ^ flip;
  const uint32_t brow = (uint32_t)((wn & 1) * 64 + r16);
  const uint32_t boff0 = ((uint32_t)(brow * 128 + kg * 16)) ^ flip;
  const uint32_t boff1 = ((uint32_t)(brow * 128 + 64 + kg * 16)) ^ flip;
  const uint32_t aHalfSel = (uint32_t)wm * 16384;
  const uint32_t bHalfSel = (uint32_t)(wn >> 1) * 16384;

  const int rowB = tm * 256 + wm * 128 + kg * 4;
  const int colL = wn * 64 + r16;  // col within a 256-group

  // bias for group 0 (oldest vm ops; retired by prologue vmcnt(4))
  float bvv[4];
#pragma unroll
  for (int n = 0; n < 4; ++n) bvv[n] = bias[colL + n * 16];

  f32x4_t acc[8][4] = {};
  f32x4_t acc2[8][4];
  bf16x8_t aq[4][2], bl[2][2], bh[2][2];

  // prologue (g=0): Blo0,Alo0,Bhi0,Ahi0,Blo1,Alo1; vmcnt(4) leaves Blo1+Alo1
  STAGE(B, LDS_B, 0, 0, 0);
  STAGE(Ab, LDS_A, 0, 0, 0);
  STAGE(B, LDS_B, 0, 1, 0);
  STAGE(Ab, LDS_A, 0, 1, 0);
  STAGE(B, LDS_B, 1, 0, 32768);
  STAGE(Ab, LDS_A, 1, 0, 32768);
  asm volatile("s_waitcnt vmcnt(4)");
  __builtin_amdgcn_s_barrier();

#pragma unroll 2
  for (int u = 0; u < 64; ++u) {
    // ---- group rollover: snapshot finished acc (+bias), reset, reload bvv --
    if ((u & 15) == 0 && u > 0) {
#pragma unroll
      for (int m = 0; m < 8; ++m)
#pragma unroll
        for (int n = 0; n < 4; ++n)
#pragma unroll
          for (int r = 0; r < 4; ++r) {
            acc2[m][n][r] = acc[m][n][r] + bvv[n];
            acc[m][n][r] = 0.f;
          }
      const int gn = u >> 4;  // bias for the group now starting (used at next copy / final)
#pragma unroll
      for (int n = 0; n < 4; ++n) bvv[n] = bias[gn * 256 + colL + n * 16];
    }
    // ---- spread stores: 8 per tile from acc2 (groups 0..2 over u=16..63) ---
    if (u >= 16) {
      const int colB2 = ((u >> 4) - 1) * 256 + colL;
      switch (u & 15) {
        STCASE(0) STCASE(1) STCASE(2) STCASE(3)
        STCASE(4) STCASE(5) STCASE(6) STCASE(7)
        STCASE(8) STCASE(9) STCASE(10) STCASE(11)
        STCASE(12) STCASE(13) STCASE(14) STCASE(15)
      }
    }

    const uint32_t co = (uint32_t)(u & 1) << 15;
    const uint32_t no = co ^ 32768u;
    const char* a0 = lds + LDS_A + co + aHalfSel + aoff0;
    const char* a1 = lds + LDS_A + co + aHalfSel + aoff1;
    const char* b0 = lds + LDS_B + co + bHalfSel + boff0;
    const char* b1 = lds + LDS_B + co + bHalfSel + boff1;

    // ---- phase 0: rd A m0-3 + B n0-1 ; stage Bhi(u+1) ----
#pragma unroll
    for (int m = 0; m < 4; ++m) { aq[m][0] = RD(a0 + m * 2048); aq[m][1] = RD(a1 + m * 2048); }
#pragma unroll
    for (int n = 0; n < 2; ++n) { bl[n][0] = RD(b0 + n * 2048); bl[n][1] = RD(b1 + n * 2048); }
    if (u + 1 < 64) STAGE(B + (size_t)((u + 1) >> 4) * 256 * DM, LDS_B, (u + 1) & 15, 1, no);
    __builtin_amdgcn_s_barrier();
    asm volatile("s_waitcnt lgkmcnt(0)");
    __builtin_amdgcn_s_setprio(1);
#pragma unroll
    for (int m = 0; m < 4; ++m)
#pragma unroll
      for (int n = 0; n < 2; ++n)
#pragma unroll
        for (int ks = 0; ks < 2; ++ks)
          acc[m][n] = __builtin_amdgcn_mfma_f32_16x16x32_bf16(aq[m][ks], bl[n][ks], acc[m][n], 0, 0, 0);
    __builtin_amdgcn_s_setprio(0);
    __builtin_amdgcn_s_barrier();

    // ---- phase 1: rd B n2-3 ; stage Ahi(u+1) ----
#pragma unroll
    for (int n = 0; n < 2; ++n) { bh[n][0] = RD(b0 + (n + 2) * 2048); bh[n][1] = RD(b1 + (n + 2) * 2048); }
    if (u + 1 < 64) STAGE(Ab, LDS_A, (u + 1) & 15, 1, no);
    __builtin_amdgcn_s_barrier();
    asm volatile("s_waitcnt lgkmcnt(0)");
    __builtin_amdgcn_s_setprio(1);
#pragma unroll
    for (int m = 0; m < 4; ++m)
#pragma unroll
      for (int n = 0; n < 2; ++n)
#pragma unroll
        for (int ks = 0; ks < 2; ++ks)
          acc[m][n + 2] = __builtin_amdgcn_mfma_f32_16x16x32_bf16(aq[m][ks], bh[n][ks], acc[m][n + 2], 0, 0, 0);
    __builtin_amdgcn_s_setprio(0);
    __builtin_amdgcn_s_barrier();

    // ---- phase 2: rd A m4-7 ; stage Blo(u+2) ----
#pragma unroll
    for (int m = 0; m < 4; ++m) { aq[m][0] = RD(a0 + (m + 4) * 2048); aq[m][1] = RD(a1 + (m + 4) * 2048); }
    if (u + 2 < 64) STAGE(B + (size_t)((u + 2) >> 4) * 256 * DM, LDS_B, (u + 2) & 15, 0, co);
    __builtin_amdgcn_s_barrier();
    asm volatile("s_waitcnt lgkmcnt(0)");
    __builtin_amdgcn_s_setprio(1);
#pragma unroll
    for (int m = 0; m < 4; ++m)
#pragma unroll
      for (int n = 0; n < 2; ++n)
#pragma unroll
        for (int ks = 0; ks < 2; ++ks)
          acc[m + 4][n] = __builtin_amdgcn_mfma_f32_16x16x32_bf16(aq[m][ks], bl[n][ks], acc[m + 4][n], 0, 0, 0);
    __builtin_amdgcn_s_setprio(0);
    __builtin_amdgcn_s_barrier();

    // ---- phase 3: stage Alo(u+2) ; tile-end counted wait ----
    if (u + 2 < 64) STAGE(Ab, LDS_A, (u + 2) & 15, 0, co);
    __builtin_amdgcn_s_barrier();
    __builtin_amdgcn_s_setprio(1);
#pragma unroll
    for (int m = 0; m < 4; ++m)
#pragma unroll
      for (int n = 0; n < 2; ++n)
#pragma unroll
        for (int ks = 0; ks < 2; ++ks)
          acc[m + 4][n + 2] = __builtin_amdgcn_mfma_f32_16x16x32_bf16(aq[m][ks], bh[n][ks], acc[m + 4][n + 2], 0, 0, 0);
    __builtin_amdgcn_s_setprio(0);
    if (u <= 61)      asm volatile("s_waitcnt vmcnt(4)");
    else if (u == 62) asm volatile("s_waitcnt vmcnt(0)");
    __builtin_amdgcn_s_barrier();
  }

  // ---- final epilogue: group 3 directly from acc (+bvv loaded at u=48) ----
  const int colB = 3 * 256 + colL;
#pragma unroll
  for (int m = 0; m < 8; ++m) {
#pragma unroll
    for (int r = 0; r < 4; ++r) {
      float* cp = C + (size_t)(rowB + m * 16 + r) * DM + colB;
#pragma unroll
      for (int n = 0; n < 4; ++n) cp[n * 16] = acc[m][n][r] + bvv[n];
    }
  }
}

extern "C" void kernel_launch(void* const* d_in, const int* in_sizes, int n_in,
                              void* d_out, int out_size, void* d_ws, size_t ws_size,
                              hipStream_t stream) {
  const float* h = (const float*)d_in[0];
  const float* pat = (const float*)d_in[1];
  const float* w = (const float*)d_in[2];
  const float* b = (const float*)d_in[3];
  float* out = (float*)d_out;
  const int M = in_sizes[0] / DM;  // 65536

  u16* Wb = (u16*)d_ws;                     // 2 MiB
  u16* Abf = (u16*)d_ws + (size_t)DM * DM;  // 128 MiB

  k0_cvt_w<<<DM * DM / 4 / 256, 256, 0, stream>>>(w, Wb);
  k1_hopfield<<<2048, 256, 0, stream>>>(h, pat, Abf, M);
  k2_gemm<<<M / 256, 512, 0, stream>>>(Abf, Wb, b, out, M);
}

// Round 9
// 227.265 us; speedup vs baseline: 1.7589x; 1.7589x over previous
//
#include <hip/hip_runtime.h>
#include <hip/hip_bf16.h>
#include <stdint.h>

#define DM 1024
#define NPAT 8
#define NKT 16  // K-tiles of 64: 1024/64
#define LDS_A 0
#define LDS_B 65536

typedef __bf16 bf16x8_t __attribute__((ext_vector_type(8)));
typedef float f32x4_t __attribute__((ext_vector_type(4)));
typedef unsigned short u16;

typedef const __attribute__((address_space(1))) void* gas_ptr;
typedef __attribute__((address_space(3))) void* las_ptr;

__device__ __forceinline__ u16 f2bf(float x) {
  uint32_t u = __float_as_uint(x);
  uint32_t r = (u + 0x7FFFu + ((u >> 16) & 1u)) >> 16;  // RNE
  return (u16)r;
}

// ---------------- K1: W-convert (blocks 0..1023) + hopfield read ------------
// W->bf16 folded in from the old k0: blocks < 1024 each convert 1024 elems
// (one float4/thread) — removes a launch and the 4us serial kernel.
// nt-loads on h (read-once stream) keep L2/L3 for Abf (verified win, R6/R7).
__global__ __launch_bounds__(256) void k1_hopfield(const float* __restrict__ h,
                                                   const float* __restrict__ pat,
                                                   const float* __restrict__ w,
                                                   u16* __restrict__ wb,
                                                   u16* __restrict__ A, int M) {
  const int tid = threadIdx.x;
  if (blockIdx.x < 1024) {
    int i = blockIdx.x * 256 + tid;
    float4 v = ((const float4*)w)[i];
    ushort4 o;
    o.x = f2bf(v.x); o.y = f2bf(v.y); o.z = f2bf(v.z); o.w = f2bf(v.w);
    ((ushort4*)wb)[i] = o;
  }

  __shared__ float patL[NPAT * DM];
  {
    const float4* p4 = (const float4*)pat;
    float4* l4 = (float4*)patL;
#pragma unroll
    for (int i = 0; i < (NPAT * DM / 4) / 256; ++i)
      l4[i * 256 + tid] = p4[i * 256 + tid];
  }
  __syncthreads();

  const int lane = tid & 63;
  const int wid = (blockIdx.x << 2) | (tid >> 6);
  const int nw = gridDim.x << 2;
  const f32x4_t* h4 = (const f32x4_t*)h;
  const f32x4_t* pl4 = (const f32x4_t*)patL;
  ushort4* A4 = (ushort4*)A;

  for (int rp = wid; rp < (M >> 1); rp += nw) {
    const size_t r0 = (size_t)rp << 1;
    f32x4_t hv0[4], hv1[4];
#pragma unroll
    for (int j = 0; j < 4; ++j) {
      hv0[j] = __builtin_nontemporal_load(&h4[r0 * 256 + j * 64 + lane]);
      hv1[j] = __builtin_nontemporal_load(&h4[(r0 + 1) * 256 + j * 64 + lane]);
    }
    float d0[NPAT], d1[NPAT];
#pragma unroll
    for (int p = 0; p < NPAT; ++p) {
      float a = 0.f, b = 0.f;
#pragma unroll
      for (int j = 0; j < 4; ++j) {
        f32x4_t pv = pl4[p * 256 + j * 64 + lane];
#pragma unroll
        for (int e = 0; e < 4; ++e) {
          a = fmaf(hv0[j][e], pv[e], a);
          b = fmaf(hv1[j][e], pv[e], b);
        }
      }
      d0[p] = a; d1[p] = b;
    }
#pragma unroll
    for (int p = 0; p < NPAT; ++p) {
#pragma unroll
      for (int o = 32; o > 0; o >>= 1) {
        d0[p] += __shfl_xor(d0[p], o);
        d1[p] += __shfl_xor(d1[p], o);
      }
    }
    float m0 = d0[0], m1 = d1[0];
#pragma unroll
    for (int p = 1; p < NPAT; ++p) { m0 = fmaxf(m0, d0[p]); m1 = fmaxf(m1, d1[p]); }
    float s0 = 0.f, s1 = 0.f;
#pragma unroll
    for (int p = 0; p < NPAT; ++p) {
      d0[p] = __expf(d0[p] - m0); s0 += d0[p];
      d1[p] = __expf(d1[p] - m1); s1 += d1[p];
    }
    const float i0 = 1.f / s0, i1 = 1.f / s1;
#pragma unroll
    for (int p = 0; p < NPAT; ++p) { d0[p] *= i0; d1[p] *= i1; }

#pragma unroll
    for (int j = 0; j < 4; ++j) {
      f32x4_t a0 = hv0[j], a1 = hv1[j];
#pragma unroll
      for (int p = 0; p < NPAT; ++p) {
        f32x4_t pv = pl4[p * 256 + j * 64 + lane];
#pragma unroll
        for (int e = 0; e < 4; ++e) {
          a0[e] = fmaf(d0[p], pv[e], a0[e]);
          a1[e] = fmaf(d1[p], pv[e], a1[e]);
        }
      }
      ushort4 o0, o1;
      o0.x = f2bf(a0[0]); o0.y = f2bf(a0[1]); o0.z = f2bf(a0[2]); o0.w = f2bf(a0[3]);
      o1.x = f2bf(a1[0]); o1.y = f2bf(a1[1]); o1.z = f2bf(a1[2]); o1.w = f2bf(a1[3]);
      A4[r0 * 256 + j * 64 + lane] = o0;
      A4[(r0 + 1) * 256 + j * 64 + lane] = o1;
    }
  }
}

// ---------------- K2: 256x256 8-phase bf16 GEMM (R7-verified, unchanged) ----
// 1024 blocks (tm x tn), XCD-bijective swizzle, temporal C stores. Plateau of
// the plain-HIP template family (~886 TF here; m97/m201/m248 all converge
// ~850-910 on comparable shapes). Persistent variants capped by vmcnt
// store-drain (R4/R8); 2-block/CU variants infeasible (VGPR/LDS).
#define STAGE(matBase, regionOff, kt, hf, bufOff)                                        \
  do {                                                                                   \
    const u16* _s = (matBase) + (size_t)((hf)*128) * DM + (kt)*64;                       \
    char* _d = lds + (regionOff) + (bufOff) + (hf)*16384;                                \
    __builtin_amdgcn_global_load_lds((gas_ptr)(_s + go0), (las_ptr)(_d + L0), 16, 0, 0); \
    __builtin_amdgcn_global_load_lds((gas_ptr)(_s + go1), (las_ptr)(_d + L1), 16, 0, 0); \
  } while (0)

#define RD(p) (*(const bf16x8_t*)(p))

__global__ __launch_bounds__(512, 2) void k2_gemm(const u16* __restrict__ A,
                                                  const u16* __restrict__ B,
                                                  const float* __restrict__ bias,
                                                  float* __restrict__ C, int M) {
  __shared__ __align__(16) char lds[131072];
  const int tid = threadIdx.x;
  const int lane = tid & 63;
  const int wave = tid >> 6;   // 0..7
  const int wm = wave >> 2;    // 0..1 -> A half
  const int wn = wave & 3;     // 0..3 -> B rows wn*64..+63
  const int r16 = lane & 15, kg = lane >> 4;

  const int bid = blockIdx.x;
  const int swz = (bid & 7) * 128 + (bid >> 3);
  const int tn = swz & 3, tm = swz >> 2;

  const u16* Ab = A + (size_t)tm * 256 * DM;
  const u16* Bb = B + (size_t)tn * 256 * DM;

  const uint32_t L0 = (uint32_t)tid * 16;
  const uint32_t L1 = 8192u + (uint32_t)tid * 16;
  const uint32_t S0 = L0 ^ (((L0 >> 7) & 7u) << 4);
  const uint32_t S1 = L1 ^ (((L1 >> 7) & 7u) << 4);
  const uint32_t go0 = (S0 >> 7) * DM + ((S0 & 127u) >> 1);
  const uint32_t go1 = (S1 >> 7) * DM + ((S1 & 127u) >> 1);

  const uint32_t flip = (uint32_t)(r16 & 7) << 4;
  const uint32_t aoff0 = ((uint32_t)(r16 * 128 + kg * 16)) ^ flip;
  const uint32_t aoff1 = ((uint32_t)(r16 * 128 + 64 + kg * 16)) ^ flip;
  const uint32_t brow = (uint32_t)((wn & 1) * 64 + r16);
  const uint32_t boff0 = ((uint32_t)(brow * 128 + kg * 16)) ^ flip;
  const uint32_t boff1 = ((uint32_t)(brow * 128 + 64 + kg * 16)) ^ flip;
  const uint32_t aHalfSel = (uint32_t)wm * 16384;
  const uint32_t bHalfSel = (uint32_t)(wn >> 1) * 16384;

  f32x4_t acc[8][4] = {};
  bf16x8_t aq[4][2], bl[2][2], bh[2][2];

  STAGE(Bb, LDS_B, 0, 0, 0);
  STAGE(Ab, LDS_A, 0, 0, 0);
  STAGE(Bb, LDS_B, 0, 1, 0);
  STAGE(Ab, LDS_A, 0, 1, 0);
  STAGE(Bb, LDS_B, 1, 0, 32768);
  STAGE(Ab, LDS_A, 1, 0, 32768);
  asm volatile("s_waitcnt vmcnt(4)");
  __builtin_amdgcn_s_barrier();

  for (int t = 0; t < NKT; ++t) {
    const uint32_t co = (uint32_t)(t & 1) << 15;
    const uint32_t no = co ^ 32768u;
    const char* a0 = lds + LDS_A + co + aHalfSel + aoff0;
    const char* a1 = lds + LDS_A + co + aHalfSel + aoff1;
    const char* b0 = lds + LDS_B + co + bHalfSel + boff0;
    const char* b1 = lds + LDS_B + co + bHalfSel + boff1;

    // ---- phase 0: A m0-3, B n0-1 ; stage Bhi(t+1) ----
#pragma unroll
    for (int m = 0; m < 4; ++m) { aq[m][0] = RD(a0 + m * 2048); aq[m][1] = RD(a1 + m * 2048); }
#pragma unroll
    for (int n = 0; n < 2; ++n) { bl[n][0] = RD(b0 + n * 2048); bl[n][1] = RD(b1 + n * 2048); }
    if (t + 1 < NKT) STAGE(Bb, LDS_B, t + 1, 1, no);
    __builtin_amdgcn_s_barrier();
    asm volatile("s_waitcnt lgkmcnt(0)");
    __builtin_amdgcn_s_setprio(1);
#pragma unroll
    for (int m = 0; m < 4; ++m)
#pragma unroll
      for (int n = 0; n < 2; ++n)
#pragma unroll
        for (int ks = 0; ks < 2; ++ks)
          acc[m][n] = __builtin_amdgcn_mfma_f32_16x16x32_bf16(aq[m][ks], bl[n][ks], acc[m][n], 0, 0, 0);
    __builtin_amdgcn_s_setprio(0);
    __builtin_amdgcn_s_barrier();

    // ---- phase 1: B n2-3 ; stage Ahi(t+1) ----
#pragma unroll
    for (int n = 0; n < 2; ++n) { bh[n][0] = RD(b0 + (n + 2) * 2048); bh[n][1] = RD(b1 + (n + 2) * 2048); }
    if (t + 1 < NKT) STAGE(Ab, LDS_A, t + 1, 1, no);
    __builtin_amdgcn_s_barrier();
    asm volatile("s_waitcnt lgkmcnt(0)");
    __builtin_amdgcn_s_setprio(1);
#pragma unroll
    for (int m = 0; m < 4; ++m)
#pragma unroll
      for (int n = 0; n < 2; ++n)
#pragma unroll
        for (int ks = 0; ks < 2; ++ks)
          acc[m][n + 2] = __builtin_amdgcn_mfma_f32_16x16x32_bf16(aq[m][ks], bh[n][ks], acc[m][n + 2], 0, 0, 0);
    __builtin_amdgcn_s_setprio(0);
    __builtin_amdgcn_s_barrier();

    // ---- phase 2: A m4-7 ; stage Blo(t+2) ----
#pragma unroll
    for (int m = 0; m < 4; ++m) { aq[m][0] = RD(a0 + (m + 4) * 2048); aq[m][1] = RD(a1 + (m + 4) * 2048); }
    if (t + 2 < NKT) STAGE(Bb, LDS_B, t + 2, 0, co);
    __builtin_amdgcn_s_barrier();
    asm volatile("s_waitcnt lgkmcnt(0)");
    __builtin_amdgcn_s_setprio(1);
#pragma unroll
    for (int m = 0; m < 4; ++m)
#pragma unroll
      for (int n = 0; n < 2; ++n)
#pragma unroll
        for (int ks = 0; ks < 2; ++ks)
          acc[m + 4][n] = __builtin_amdgcn_mfma_f32_16x16x32_bf16(aq[m][ks], bl[n][ks], acc[m + 4][n], 0, 0, 0);
    __builtin_amdgcn_s_setprio(0);
    __builtin_amdgcn_s_barrier();

    // ---- phase 3: stage Alo(t+2) ; tile-end counted wait ----
    if (t + 2 < NKT) STAGE(Ab, LDS_A, t + 2, 0, co);
    __builtin_amdgcn_s_barrier();
    __builtin_amdgcn_s_setprio(1);
#pragma unroll
    for (int m = 0; m < 4; ++m)
#pragma unroll
      for (int n = 0; n < 2; ++n)
#pragma unroll
        for (int ks = 0; ks < 2; ++ks)
          acc[m + 4][n + 2] = __builtin_amdgcn_mfma_f32_16x16x32_bf16(aq[m][ks], bh[n][ks], acc[m + 4][n + 2], 0, 0, 0);
    __builtin_amdgcn_s_setprio(0);
    if (t < NKT - 1) {
      if (t + 2 < NKT) asm volatile("s_waitcnt vmcnt(4)");
      else             asm volatile("s_waitcnt vmcnt(0)");
    }
    __builtin_amdgcn_s_barrier();
  }

  const int colB = tn * 256 + wn * 64 + r16;
  const int rowB = tm * 256 + wm * 128 + kg * 4;
  float bvv[4];
#pragma unroll
  for (int n = 0; n < 4; ++n) bvv[n] = bias[colB + n * 16];
#pragma unroll
  for (int m = 0; m < 8; ++m) {
#pragma unroll
    for (int r = 0; r < 4; ++r) {
      float* cp = C + (size_t)(rowB + m * 16 + r) * DM + colB;
#pragma unroll
      for (int n = 0; n < 4; ++n) cp[n * 16] = acc[m][n][r] + bvv[n];
    }
  }
}

extern "C" void kernel_launch(void* const* d_in, const int* in_sizes, int n_in,
                              void* d_out, int out_size, void* d_ws, size_t ws_size,
                              hipStream_t stream) {
  const float* h = (const float*)d_in[0];
  const float* pat = (const float*)d_in[1];
  const float* w = (const float*)d_in[2];
  const float* b = (const float*)d_in[3];
  float* out = (float*)d_out;
  const int M = in_sizes[0] / DM;  // 65536

  u16* Wb = (u16*)d_ws;                     // 2 MiB
  u16* Abf = (u16*)d_ws + (size_t)DM * DM;  // 128 MiB

  k1_hopfield<<<2048, 256, 0, stream>>>(h, pat, w, Wb, Abf, M);
  k2_gemm<<<(M / 256) * (DM / 256), 512, 0, stream>>>(Abf, Wb, b, out, M);
}